// Round 1
// baseline (1309.032 us; speedup 1.0000x reference)
//
#include <hip/hip_runtime.h>

// Decoder_21208548508049: fused LIF-SNN decoder, exact-f32 baseline.
// inp = x @ W_lif + b_lif ; LIF recurrence over T (tau=2, vth=1, hard reset);
// g = x*(1-sp) ; out = g @ W_rec + b_rec.
//
// Layout: T=32,B=8,N=256,D=512. Block = one (b,n) token, 256 threads.
// Thread j owns columns {2j,2j+1} for ALL t -> recurrence is thread-local.

#define TT 32
#define BB 8
#define NN 256
#define DD 512

__global__ __launch_bounds__(256, 2) void lif_decoder_f32(
    const float* __restrict__ x,      // [T,B,N,D]
    const float* __restrict__ tr_mx,  // [B,N,D]
    const float* __restrict__ Wl,     // [D,D]  (d,e) at d*D+e
    const float* __restrict__ bl,     // [D]
    const float* __restrict__ Wr,     // [D,D]
    const float* __restrict__ br,     // [D]
    float* __restrict__ out)          // [T,B,N,D]
{
    __shared__ float xs[TT][DD];          // 64 KB; holds x, then g (in place)

    const int tid = threadIdx.x;          // 0..255
    const int tok = blockIdx.x;           // 0..2047 == b*N+n
    const int e0  = tid * 2;
    const size_t base = (size_t)tok * DD;
    const size_t st   = (size_t)BB * NN * DD;   // t-stride = 1048576

    // ---- phase 0: stage x token into LDS (coalesced float2) ----
    #pragma unroll
    for (int t = 0; t < TT; ++t) {
        float2 v = *reinterpret_cast<const float2*>(&x[t * st + base + e0]);
        *reinterpret_cast<float2*>(&xs[t][e0]) = v;
    }
    __syncthreads();

    // ---- phase 1: GEMM1  acc[t][{0,1}] = x[t,:] @ Wl[:, e0..e0+1] + bl ----
    float acc0[TT], acc1[TT];
    {
        const float bl0 = bl[e0], bl1 = bl[e0 + 1];
        #pragma unroll
        for (int t = 0; t < TT; ++t) { acc0[t] = bl0; acc1[t] = bl1; }
    }
    #pragma unroll 2
    for (int d = 0; d < DD; d += 4) {
        const float2 w0 = *reinterpret_cast<const float2*>(&Wl[(size_t)(d + 0) * DD + e0]);
        const float2 w1 = *reinterpret_cast<const float2*>(&Wl[(size_t)(d + 1) * DD + e0]);
        const float2 w2 = *reinterpret_cast<const float2*>(&Wl[(size_t)(d + 2) * DD + e0]);
        const float2 w3 = *reinterpret_cast<const float2*>(&Wl[(size_t)(d + 3) * DD + e0]);
        #pragma unroll
        for (int t = 0; t < TT; ++t) {
            const float4 xv = *reinterpret_cast<const float4*>(&xs[t][d]);  // wave-uniform broadcast
            acc0[t] = fmaf(xv.x, w0.x, acc0[t]);
            acc1[t] = fmaf(xv.x, w0.y, acc1[t]);
            acc0[t] = fmaf(xv.y, w1.x, acc0[t]);
            acc1[t] = fmaf(xv.y, w1.y, acc1[t]);
            acc0[t] = fmaf(xv.z, w2.x, acc0[t]);
            acc1[t] = fmaf(xv.z, w2.y, acc1[t]);
            acc0[t] = fmaf(xv.w, w3.x, acc0[t]);
            acc1[t] = fmaf(xv.w, w3.y, acc1[t]);
        }
    }
    __syncthreads();   // all phase-1 LDS reads done before g overwrites xs

    // ---- phase 2: LIF recurrence (thread-local), g = x*(1-sp) into xs ----
    {
        float m0 = tr_mx[base + e0];
        float m1 = tr_mx[base + e0 + 1];
        #pragma unroll
        for (int t = 0; t < TT; ++t) {
            m0 = m0 + (acc0[t] - m0) * 0.5f;        // tau = 2
            m1 = m1 + (acc1[t] - m1) * 0.5f;
            const float s0 = (m0 - 1.0f > 0.0f) ? 1.0f : 0.0f;   // vth = 1
            const float s1 = (m1 - 1.0f > 0.0f) ? 1.0f : 0.0f;
            m0 *= (1.0f - s0);
            m1 *= (1.0f - s1);
            xs[t][e0]     *= (1.0f - s0);           // g overwrites x in place
            xs[t][e0 + 1] *= (1.0f - s1);
        }
    }
    __syncthreads();

    // ---- phase 3: GEMM2  out[t, e0..e0+1] = g[t,:] @ Wr[:, e0..e0+1] + br ----
    {
        const float br0 = br[e0], br1 = br[e0 + 1];
        #pragma unroll
        for (int t = 0; t < TT; ++t) { acc0[t] = br0; acc1[t] = br1; }
    }
    #pragma unroll 2
    for (int d = 0; d < DD; d += 4) {
        const float2 w0 = *reinterpret_cast<const float2*>(&Wr[(size_t)(d + 0) * DD + e0]);
        const float2 w1 = *reinterpret_cast<const float2*>(&Wr[(size_t)(d + 1) * DD + e0]);
        const float2 w2 = *reinterpret_cast<const float2*>(&Wr[(size_t)(d + 2) * DD + e0]);
        const float2 w3 = *reinterpret_cast<const float2*>(&Wr[(size_t)(d + 3) * DD + e0]);
        #pragma unroll
        for (int t = 0; t < TT; ++t) {
            const float4 gv = *reinterpret_cast<const float4*>(&xs[t][d]);
            acc0[t] = fmaf(gv.x, w0.x, acc0[t]);
            acc1[t] = fmaf(gv.x, w0.y, acc1[t]);
            acc0[t] = fmaf(gv.y, w1.x, acc0[t]);
            acc1[t] = fmaf(gv.y, w1.y, acc1[t]);
            acc0[t] = fmaf(gv.z, w2.x, acc0[t]);
            acc1[t] = fmaf(gv.z, w2.y, acc1[t]);
            acc0[t] = fmaf(gv.w, w3.x, acc0[t]);
            acc1[t] = fmaf(gv.w, w3.y, acc1[t]);
        }
    }

    // ---- store (coalesced float2) ----
    #pragma unroll
    for (int t = 0; t < TT; ++t) {
        float2 v;
        v.x = acc0[t];
        v.y = acc1[t];
        *reinterpret_cast<float2*>(&out[t * st + base + e0]) = v;
    }
}

extern "C" void kernel_launch(void* const* d_in, const int* in_sizes, int n_in,
                              void* d_out, int out_size, void* d_ws, size_t ws_size,
                              hipStream_t stream) {
    const float* x     = (const float*)d_in[0];
    const float* tr_mx = (const float*)d_in[1];
    const float* Wl    = (const float*)d_in[2];
    const float* bl    = (const float*)d_in[3];
    const float* Wr    = (const float*)d_in[4];
    const float* br    = (const float*)d_in[5];
    float* out = (float*)d_out;

    dim3 grid(BB * NN);   // 2048 token blocks
    dim3 block(256);
    lif_decoder_f32<<<grid, block, 0, stream>>>(x, tr_mx, Wl, bl, Wr, br, out);
}